// Round 10
// baseline (169.415 us; speedup 1.0000x reference)
//
#include <hip/hip_runtime.h>
#include <hip/hip_fp16.h>

#define THREADS 256
#define EPB 2048   // edges per block in hist/scat (256 thr x 8)
#define LDK 136    // padded K-stride for fp16 LDS tiles (128 + 8)

using f16x8 = __attribute__((ext_vector_type(8))) _Float16;
using f32x4 = __attribute__((ext_vector_type(4))) float;

// ---------------- weight pre-convert: wt1h[nn][kk] = fp16(W1[kk][nn]); wt2h padded to 48 rows ----------------
__global__ __launch_bounds__(256) void k_wcvt(const float* __restrict__ W1,
                                              const float* __restrict__ W2,
                                              __half* __restrict__ wt1,
                                              __half* __restrict__ wt2) {
    const int idx = blockIdx.x * 256 + threadIdx.x;
    if (idx < 128 * 128) {
        const int nn = idx >> 7, kk = idx & 127;
        wt1[idx] = __float2half(W1[kk * 128 + nn]);
    } else {
        const int o = idx - 128 * 128;
        if (o < 48 * 128) {
            const int nn = o >> 7, kk = o & 127;
            wt2[o] = (nn < 40) ? __float2half(W2[kk * 40 + nn]) : __half(0.f);
        }
    }
}

// ================= sort-based CSR build (no global atomics) =================

__global__ __launch_bounds__(256) void k_hist(const int* __restrict__ dst,
                                              int* __restrict__ Hmat,
                                              int e, int nbuck, int nbpad) {
    __shared__ int h[256];
    const int t = threadIdx.x;
    h[t] = 0;
    __syncthreads();
    const int base4 = blockIdx.x * 512;   // int4 units
#pragma unroll
    for (int k = 0; k < 2; ++k) {
        const int i4 = base4 + k * 256 + t;
        const int i = i4 * 4;
        if (i + 3 < e) {
            const int4 d4 = ((const int4*)dst)[i4];
            atomicAdd(&h[d4.x >> 8], 1);
            atomicAdd(&h[d4.y >> 8], 1);
            atomicAdd(&h[d4.z >> 8], 1);
            atomicAdd(&h[d4.w >> 8], 1);
        } else {
            for (int j = i; j < e; ++j) atomicAdd(&h[dst[j] >> 8], 1);
        }
    }
    __syncthreads();
    if (t < nbuck) Hmat[t * nbpad + blockIdx.x] = h[t];
}

__global__ __launch_bounds__(256) void k_bscan(const int* __restrict__ Hmat,
                                               int* __restrict__ Off,
                                               int* __restrict__ btot,
                                               int nb, int nbpad) {
    __shared__ int s[256];
    const int b = blockIdx.x, t = threadIdx.x;
    const int* H = Hmat + b * nbpad;
    const int v0 = (2 * t     < nb) ? H[2 * t]     : 0;
    const int v1 = (2 * t + 1 < nb) ? H[2 * t + 1] : 0;
    const int p = v0 + v1;
    s[t] = p;
    __syncthreads();
    for (int off = 1; off < 256; off <<= 1) {
        int w = (t >= off) ? s[t - off] : 0;
        __syncthreads();
        s[t] += w;
        __syncthreads();
    }
    const int excl = s[t] - p;
    int* O = Off + b * nbpad;
    if (2 * t     < nb) O[2 * t]     = excl;
    if (2 * t + 1 < nb) O[2 * t + 1] = excl + v0;
    if (t == 255) btot[b] = s[255];
}

// scatter packed (src<<8 | dst&255) into coarse buckets; combined base table in LDS
__global__ __launch_bounds__(256) void k_scat(const int* __restrict__ src,
                                              const int* __restrict__ dst,
                                              const int* __restrict__ Off,
                                              const int* __restrict__ btot,
                                              int* __restrict__ sorted,
                                              int e, int nbuck, int nbpad) {
    __shared__ int h[256];
    __shared__ int sc[256];
    __shared__ int comb[256];   // bbase[b] + Off[b][this block]
    const int t = threadIdx.x;
    const int v = (t < nbuck) ? btot[t] : 0;
    h[t] = 0;
    sc[t] = v;
    __syncthreads();
    for (int off = 1; off < 256; off <<= 1) {
        int w = (t >= off) ? sc[t - off] : 0;
        __syncthreads();
        sc[t] += w;
        __syncthreads();
    }
    comb[t] = (sc[t] - v) + ((t < nbuck) ? Off[t * nbpad + blockIdx.x] : 0);
    __syncthreads();

    const int base4 = blockIdx.x * 512;
#pragma unroll
    for (int k = 0; k < 2; ++k) {
        const int i4 = base4 + k * 256 + t;
        const int i = i4 * 4;
        if (i + 3 < e) {
            const int4 s4 = ((const int4*)src)[i4];
            const int4 d4 = ((const int4*)dst)[i4];
            {
                const int b = d4.x >> 8;
                sorted[comb[b] + atomicAdd(&h[b], 1)] = (s4.x << 8) | (d4.x & 255);
            }
            {
                const int b = d4.y >> 8;
                sorted[comb[b] + atomicAdd(&h[b], 1)] = (s4.y << 8) | (d4.y & 255);
            }
            {
                const int b = d4.z >> 8;
                sorted[comb[b] + atomicAdd(&h[b], 1)] = (s4.z << 8) | (d4.z & 255);
            }
            {
                const int b = d4.w >> 8;
                sorted[comb[b] + atomicAdd(&h[b], 1)] = (s4.w << 8) | (d4.w & 255);
            }
        } else {
            for (int j = i; j < e; ++j) {
                const int d = dst[j];
                const int b = d >> 8;
                sorted[comb[b] + atomicAdd(&h[b], 1)] = (src[j] << 8) | (d & 255);
            }
        }
    }
}

// per-bucket counting sort by packed low byte -> csr_src contiguous; emits rowptr + dinv
__global__ __launch_bounds__(256) void k_bsort(const int* __restrict__ sorted,
                                               const int* __restrict__ btot,
                                               int* __restrict__ csr_src,
                                               int* __restrict__ rowptr,
                                               float* __restrict__ dinv,
                                               int n, int nbuck, int e) {
    __shared__ int cnt[256];
    __shared__ int s[256];
    __shared__ int fil[256];
    const int b = blockIdx.x, t = threadIdx.x;

    const int v = (t < nbuck) ? btot[t] : 0;
    s[t] = v;
    cnt[t] = 0;
    __syncthreads();
    for (int off = 1; off < 256; off <<= 1) {
        int w = (t >= off) ? s[t - off] : 0;
        __syncthreads();
        s[t] += w;
        __syncthreads();
    }
    const int hi = s[b];
    const int lo = hi - btot[b];
    __syncthreads();

    for (int p = lo + t; p < hi; p += 256) atomicAdd(&cnt[sorted[p] & 255], 1);
    __syncthreads();
    const int c = cnt[t];
    s[t] = c;
    __syncthreads();
    for (int off = 1; off < 256; off <<= 1) {
        int w = (t >= off) ? s[t - off] : 0;
        __syncthreads();
        s[t] += w;
        __syncthreads();
    }
    const int excl = s[t] - c;
    const int node = b * 256 + t;
    if (node < n) {
        rowptr[node] = lo + excl;
        dinv[node] = rsqrtf((float)(c + 1));
    }
    if (b == 0 && t == 0) rowptr[n] = e;
    fil[t] = lo + excl;
    __syncthreads();
    for (int p = lo + t; p < hi; p += 256) {
        const int pr = sorted[p];
        const int pos = atomicAdd(&fil[pr & 255], 1);
        csr_src[pos] = pr >> 8;
    }
}

// ---------------- GEMM1 (MFMA f16): g1 slabs[4][n_pad][32](fp16) = dinv * (x @ W1) ----------------
__global__ __launch_bounds__(256) void k_gemm1(const float* __restrict__ x,
                                               const __half* __restrict__ wt1,
                                               const float* __restrict__ dinv,
                                               __half* __restrict__ g, int n, int n_pad) {
    __shared__ _Float16 Wt[128 * LDK];  // W^T [nn][kk], 34816 B
    __shared__ _Float16 xl[64 * LDK];   // x   [r][kk], 17408 B
    const int t  = threadIdx.x;
    const int wv = t >> 6;
    const int l  = t & 63;
    const int base = blockIdx.x * 64;
    const size_t slabstride = (size_t)n_pad * 32;

    {
        const uint4* Wg = (const uint4*)wt1;
#pragma unroll
        for (int i = 0; i < 8; ++i) {
            const int idx = t + 256 * i;
            const int row = idx >> 4, c8 = idx & 15;
            *(uint4*)(Wt + row * LDK + c8 * 8) = Wg[idx];
        }
    }
#pragma unroll
    for (int i = 0; i < 8; ++i) {
        const int idx = t + 256 * i;
        const int r = idx >> 5, c4 = idx & 31;
        const int row = base + r;
        float4 v = make_float4(0.f, 0.f, 0.f, 0.f);
        if (row < n) v = *(const float4*)(x + (size_t)row * 128 + c4 * 4);
        union { __half2 h2[2]; uint2 u; } pk;
        pk.h2[0] = __floats2half2_rn(v.x, v.y);
        pk.h2[1] = __floats2half2_rn(v.z, v.w);
        *(uint2*)(xl + r * LDK + c4 * 4) = pk.u;
    }
    __syncthreads();

    f32x4 acc[8];
#pragma unroll
    for (int i = 0; i < 8; ++i) acc[i] = (f32x4){0.f, 0.f, 0.f, 0.f};

    const int arow = wv * 16 + (l & 15);
    const int koff = (l >> 4) * 8;
#pragma unroll
    for (int kb = 0; kb < 4; ++kb) {
        const f16x8 a = *(const f16x8*)(xl + arow * LDK + kb * 32 + koff);
#pragma unroll
        for (int nt = 0; nt < 8; ++nt) {
            const f16x8 b = *(const f16x8*)(Wt + (nt * 16 + (l & 15)) * LDK + kb * 32 + koff);
            acc[nt] = __builtin_amdgcn_mfma_f32_16x16x32_f16(a, b, acc[nt], 0, 0, 0);
        }
    }

    // C layout: row=(l>>4)*4+i, col=nt*16+(l&15); slab = nt>>1, in-slab col = (nt&1)*16+(l&15)
#pragma unroll
    for (int i = 0; i < 4; ++i) {
        const int row = base + wv * 16 + (l >> 4) * 4 + i;
        if (row < n) {
            const float dv = dinv[row];
#pragma unroll
            for (int nt = 0; nt < 8; ++nt)
                g[(nt >> 1) * slabstride + (size_t)row * 32 + (nt & 1) * 16 + (l & 15)] =
                    __float2half(acc[nt][i] * dv);
        }
    }
}

// ---------------- gather1 (slab-chunked): out1h[d] = fp16(relu(b1 + dd*(g1[d] + sum g1[s]))) ----------------
// grid (ceil(n/4), 4): y = 32-feat slab (3.2 MB, L2-resident). Wave = node;
// lane = eg*16+f: 4 edge-groups, 64B coalesced row reads, 2-deep unroll.
__global__ __launch_bounds__(256) void k_gather1(const __half2* __restrict__ g,
                                                 const int* __restrict__ rowptr,
                                                 const int* __restrict__ csr_src,
                                                 const float* __restrict__ dinv,
                                                 const float* __restrict__ b1,
                                                 __half2* __restrict__ out1,
                                                 int n, int n_pad) {
    const int wave = threadIdx.x >> 6;
    const int lane = threadIdx.x & 63;
    const int d = blockIdx.x * 4 + wave;
    if (d >= n) return;
    const int y  = blockIdx.y;
    const int f  = lane & 15;
    const int eg = lane >> 4;   // 0..3
    const __half2* gs = g + (size_t)y * n_pad * 16;
    const int beg = rowptr[d], end = rowptr[d + 1];
    float ax = 0.f, ay = 0.f, bx = 0.f, by = 0.f;
    int p = beg + eg;
    for (; p + 4 < end; p += 8) {
        const int s0 = csr_src[p], s1 = csr_src[p + 4];
        const float2 f0 = __half22float2(gs[(size_t)s0 * 16 + f]);
        const float2 f1 = __half22float2(gs[(size_t)s1 * 16 + f]);
        ax += f0.x; ay += f0.y;
        bx += f1.x; by += f1.y;
    }
    for (; p < end; p += 4) {
        const int s0 = csr_src[p];
        const float2 f0 = __half22float2(gs[(size_t)s0 * 16 + f]);
        ax += f0.x; ay += f0.y;
    }
    ax += bx; ay += by;
    ax += __shfl_xor(ax, 16); ay += __shfl_xor(ay, 16);
    ax += __shfl_xor(ax, 32); ay += __shfl_xor(ay, 32);
    if (eg == 0) {
        const float2 fs = __half22float2(gs[(size_t)d * 16 + f]);
        ax += fs.x; ay += fs.y;
        const float dd = dinv[d];
        const float2 bb = *(const float2*)(b1 + y * 32 + f * 2);
        const float rx = fmaxf(fmaf(dd, ax, bb.x), 0.f);
        const float ry = fmaxf(fmaf(dd, ay, bb.y), 0.f);
        out1[(size_t)d * 64 + y * 16 + f] = __floats2half2_rn(rx, ry);
    }
}

// ---------------- GEMM2 (MFMA f16): g2[n,40](fp16) = dinv * (out1h @ W2), N padded to 48 ----------------
__global__ __launch_bounds__(256) void k_gemm2(const __half* __restrict__ h1,
                                               const __half* __restrict__ wt2,
                                               const float* __restrict__ dinv,
                                               __half* __restrict__ g, int n) {
    __shared__ _Float16 Wt[48 * LDK];   // 13056 B
    __shared__ _Float16 xl[64 * LDK];   // 17408 B
    const int t  = threadIdx.x;
    const int wv = t >> 6;
    const int l  = t & 63;
    const int base = blockIdx.x * 64;

    {
        const uint4* Wg = (const uint4*)wt2;   // 768 uint4
#pragma unroll
        for (int i = 0; i < 3; ++i) {
            const int idx = t + 256 * i;
            const int row = idx >> 4, c8 = idx & 15;
            *(uint4*)(Wt + row * LDK + c8 * 8) = Wg[idx];
        }
    }
#pragma unroll
    for (int i = 0; i < 4; ++i) {
        const int idx = t + 256 * i;
        const int r = idx >> 4, c8 = idx & 15;
        const int row = base + r;
        uint4 v = make_uint4(0u, 0u, 0u, 0u);
        if (row < n) v = *(const uint4*)(h1 + (size_t)row * 128 + c8 * 8);
        *(uint4*)(xl + r * LDK + c8 * 8) = v;
    }
    __syncthreads();

    f32x4 acc[3];
#pragma unroll
    for (int i = 0; i < 3; ++i) acc[i] = (f32x4){0.f, 0.f, 0.f, 0.f};

    const int arow = wv * 16 + (l & 15);
    const int koff = (l >> 4) * 8;
#pragma unroll
    for (int kb = 0; kb < 4; ++kb) {
        const f16x8 a = *(const f16x8*)(xl + arow * LDK + kb * 32 + koff);
#pragma unroll
        for (int nt = 0; nt < 3; ++nt) {
            const f16x8 b = *(const f16x8*)(Wt + (nt * 16 + (l & 15)) * LDK + kb * 32 + koff);
            acc[nt] = __builtin_amdgcn_mfma_f32_16x16x32_f16(a, b, acc[nt], 0, 0, 0);
        }
    }

#pragma unroll
    for (int i = 0; i < 4; ++i) {
        const int row = base + wv * 16 + (l >> 4) * 4 + i;
        if (row < n) {
            const float dv = dinv[row];
#pragma unroll
            for (int nt = 0; nt < 3; ++nt) {
                const int col = nt * 16 + (l & 15);
                if (col < 40)
                    g[(size_t)row * 40 + col] = __float2half(acc[nt][i] * dv);
            }
        }
    }
}

// ---------------- gather2: out[d] = b2 + dinv[d]*(g2[d] + sum g2[s]) ----------------
__global__ __launch_bounds__(256) void k_gather2(const __half2* __restrict__ g,
                                                 const int* __restrict__ rowptr,
                                                 const int* __restrict__ csr_src,
                                                 const float* __restrict__ dinv,
                                                 const float* __restrict__ b2,
                                                 float* __restrict__ out, int n) {
    const int wave = threadIdx.x >> 6;
    const int lane = threadIdx.x & 63;
    const int d = blockIdx.x * 4 + wave;
    if (d >= n) return;
    const int eg = lane / 20;          // 0..2 active, 3 idle
    const int f  = lane - eg * 20;
    const int beg = rowptr[d], end = rowptr[d + 1];
    float ax = 0.f, ay = 0.f;
    if (eg < 3) {
        for (int p = beg + eg; p < end; p += 3) {
            const int s0 = csr_src[p];
            const float2 f0 = __half22float2(g[(size_t)s0 * 20 + f]);
            ax += f0.x; ay += f0.y;
        }
    }
    ax += __shfl(ax, lane + 20) + __shfl(ax, lane + 40);
    ay += __shfl(ay, lane + 20) + __shfl(ay, lane + 40);
    if (lane < 20) {
        const float2 fs = __half22float2(g[(size_t)d * 20 + lane]);
        ax += fs.x; ay += fs.y;
        const float dd = dinv[d];
        const float2 bb = *(const float2*)(b2 + lane * 2);
        float2 r;
        r.x = fmaf(dd, ax, bb.x);
        r.y = fmaf(dd, ay, bb.y);
        *(float2*)(out + (size_t)d * 40 + lane * 2) = r;
    }
}

extern "C" void kernel_launch(void* const* d_in, const int* in_sizes, int n_in,
                              void* d_out, int out_size, void* d_ws, size_t ws_size,
                              hipStream_t stream) {
    const float* x  = (const float*)d_in[0];
    const int*   ei = (const int*)d_in[1];
    const float* W1 = (const float*)d_in[2];
    const float* b1 = (const float*)d_in[3];
    const float* W2 = (const float*)d_in[4];
    const float* b2 = (const float*)d_in[5];
    float* out = (float*)d_out;

    const int n = in_sizes[0] / 128;   // 50000
    const int e = in_sizes[1] / 2;     // 800000
    const int* src = ei;
    const int* dst = ei + e;

    const int n_pad = ((n + 63) / 64) * 64;
    const int e_pad = ((e + 63) / 64) * 64;
    const int NB    = (e + EPB - 1) / EPB;        // 391
    const int nbuck = (n + 255) >> 8;             // 196
    const int nbpad = ((NB + 63) / 64) * 64;      // 448

    // ws layout (4B units):
    //   dinv[n_pad] | rowptr[n_pad+64] | csr_src[e_pad] | g1[4 slabs x n_pad x 32 fp16]
    //   | out1h[n_pad*128 fp16] | wt1h[128*128 fp16] | wt2h[48*128 fp16]
    // sorted/Hmat/Off/btot overlay g1 (dead before k_gemm1); g2 overlays g1 (dead after gather1).
    float*   ws      = (float*)d_ws;
    float*   dinv    = ws;
    int*     rowptr  = (int*)(ws + n_pad);
    int*     csr_src = rowptr + n_pad + 64;
    __half*  g1      = (__half*)(csr_src + e_pad);       // 4*n_pad*32 fp16
    __half*  out1h   = g1 + (size_t)n_pad * 128;
    __half*  wt1h    = out1h + (size_t)n_pad * 128;
    __half*  wt2h    = wt1h + 128 * 128;
    int*     sorted  = (int*)g1;                         // overlay: e_pad ints (packed)
    int*     Hmat    = (int*)g1 + e_pad;                 // overlay
    int*     Off     = Hmat + nbuck * nbpad;             // overlay
    int*     btot    = Off + nbuck * nbpad;              // overlay
    __half2* g2      = (__half2*)g1;                     // overlay

    const int nb_rows = (n + 63) / 64;
    const int nb_g    = (n + 3) / 4;

    // weight pre-convert (independent of everything else)
    k_wcvt<<<(128 * 128 + 48 * 128 + 255) / 256, 256, 0, stream>>>(W1, W2, wt1h, wt2h);

    // CSR build: 2-level bucket sort, packed payload, zero global atomics
    k_hist <<<NB,    256, 0, stream>>>(dst, Hmat, e, nbuck, nbpad);
    k_bscan<<<nbuck, 256, 0, stream>>>(Hmat, Off, btot, NB, nbpad);
    k_scat <<<NB,    256, 0, stream>>>(src, dst, Off, btot, sorted, e, nbuck, nbpad);
    k_bsort<<<nbuck, 256, 0, stream>>>(sorted, btot, csr_src, rowptr, dinv, n, nbuck, e);

    // layer 1
    k_gemm1  <<<nb_rows, 256, 0, stream>>>(x, wt1h, dinv, g1, n, n_pad);
    k_gather1<<<dim3(nb_g, 4), 256, 0, stream>>>((const __half2*)g1, rowptr, csr_src,
                                                 dinv, b1, (__half2*)out1h, n, n_pad);

    // layer 2
    k_gemm2  <<<nb_rows, 256, 0, stream>>>(out1h, wt2h, dinv, (__half*)g2, n);
    k_gather2<<<nb_g, 256, 0, stream>>>(g2, rowptr, csr_src, dinv, b2, out, n);
}

// Round 11
// 128.948 us; speedup vs baseline: 1.3138x; 1.3138x over previous
//
#include <hip/hip_runtime.h>
#include <hip/hip_fp16.h>

#define THREADS 256
#define EPB 2048   // edges per block in hist/scat (256 thr x 8)
#define LDK 136    // padded K-stride for fp16 LDS tiles (128 + 8)

using f16x8 = __attribute__((ext_vector_type(8))) _Float16;
using f32x4 = __attribute__((ext_vector_type(4))) float;

// ---------------- weight pre-convert: wt1h[nn][kk] = fp16(W1[kk][nn]); wt2h padded to 48 rows ----------------
__global__ __launch_bounds__(256) void k_wcvt(const float* __restrict__ W1,
                                              const float* __restrict__ W2,
                                              __half* __restrict__ wt1,
                                              __half* __restrict__ wt2) {
    const int idx = blockIdx.x * 256 + threadIdx.x;
    if (idx < 128 * 128) {
        const int nn = idx >> 7, kk = idx & 127;
        wt1[idx] = __float2half(W1[kk * 128 + nn]);
    } else {
        const int o = idx - 128 * 128;
        if (o < 48 * 128) {
            const int nn = o >> 7, kk = o & 127;
            wt2[o] = (nn < 40) ? __float2half(W2[kk * 40 + nn]) : __half(0.f);
        }
    }
}

// ================= sort-based CSR build (no global atomics) =================

__global__ __launch_bounds__(256) void k_hist(const int* __restrict__ dst,
                                              int* __restrict__ Hmat,
                                              int e, int nbuck, int nbpad) {
    __shared__ int h[256];
    const int t = threadIdx.x;
    h[t] = 0;
    __syncthreads();
    const int base4 = blockIdx.x * 512;   // int4 units
#pragma unroll
    for (int k = 0; k < 2; ++k) {
        const int i4 = base4 + k * 256 + t;
        const int i = i4 * 4;
        if (i + 3 < e) {
            const int4 d4 = ((const int4*)dst)[i4];
            atomicAdd(&h[d4.x >> 8], 1);
            atomicAdd(&h[d4.y >> 8], 1);
            atomicAdd(&h[d4.z >> 8], 1);
            atomicAdd(&h[d4.w >> 8], 1);
        } else {
            for (int j = i; j < e; ++j) atomicAdd(&h[dst[j] >> 8], 1);
        }
    }
    __syncthreads();
    if (t < nbuck) Hmat[t * nbpad + blockIdx.x] = h[t];
}

__global__ __launch_bounds__(256) void k_bscan(const int* __restrict__ Hmat,
                                               int* __restrict__ Off,
                                               int* __restrict__ btot,
                                               int nb, int nbpad) {
    __shared__ int s[256];
    const int b = blockIdx.x, t = threadIdx.x;
    const int* H = Hmat + b * nbpad;
    const int v0 = (2 * t     < nb) ? H[2 * t]     : 0;
    const int v1 = (2 * t + 1 < nb) ? H[2 * t + 1] : 0;
    const int p = v0 + v1;
    s[t] = p;
    __syncthreads();
    for (int off = 1; off < 256; off <<= 1) {
        int w = (t >= off) ? s[t - off] : 0;
        __syncthreads();
        s[t] += w;
        __syncthreads();
    }
    const int excl = s[t] - p;
    int* O = Off + b * nbpad;
    if (2 * t     < nb) O[2 * t]     = excl;
    if (2 * t + 1 < nb) O[2 * t + 1] = excl + v0;
    if (t == 255) btot[b] = s[255];
}

// scatter packed (src<<8 | dst&255) into coarse buckets; combined base table in LDS
__global__ __launch_bounds__(256) void k_scat(const int* __restrict__ src,
                                              const int* __restrict__ dst,
                                              const int* __restrict__ Off,
                                              const int* __restrict__ btot,
                                              int* __restrict__ sorted,
                                              int e, int nbuck, int nbpad) {
    __shared__ int h[256];
    __shared__ int sc[256];
    __shared__ int comb[256];   // bbase[b] + Off[b][this block]
    const int t = threadIdx.x;
    const int v = (t < nbuck) ? btot[t] : 0;
    h[t] = 0;
    sc[t] = v;
    __syncthreads();
    for (int off = 1; off < 256; off <<= 1) {
        int w = (t >= off) ? sc[t - off] : 0;
        __syncthreads();
        sc[t] += w;
        __syncthreads();
    }
    comb[t] = (sc[t] - v) + ((t < nbuck) ? Off[t * nbpad + blockIdx.x] : 0);
    __syncthreads();

    const int base4 = blockIdx.x * 512;
#pragma unroll
    for (int k = 0; k < 2; ++k) {
        const int i4 = base4 + k * 256 + t;
        const int i = i4 * 4;
        if (i + 3 < e) {
            const int4 s4 = ((const int4*)src)[i4];
            const int4 d4 = ((const int4*)dst)[i4];
            {
                const int b = d4.x >> 8;
                sorted[comb[b] + atomicAdd(&h[b], 1)] = (s4.x << 8) | (d4.x & 255);
            }
            {
                const int b = d4.y >> 8;
                sorted[comb[b] + atomicAdd(&h[b], 1)] = (s4.y << 8) | (d4.y & 255);
            }
            {
                const int b = d4.z >> 8;
                sorted[comb[b] + atomicAdd(&h[b], 1)] = (s4.z << 8) | (d4.z & 255);
            }
            {
                const int b = d4.w >> 8;
                sorted[comb[b] + atomicAdd(&h[b], 1)] = (s4.w << 8) | (d4.w & 255);
            }
        } else {
            for (int j = i; j < e; ++j) {
                const int d = dst[j];
                const int b = d >> 8;
                sorted[comb[b] + atomicAdd(&h[b], 1)] = (src[j] << 8) | (d & 255);
            }
        }
    }
}

// per-bucket counting sort by packed low byte -> csr_src contiguous; emits rowptr + dinv
__global__ __launch_bounds__(256) void k_bsort(const int* __restrict__ sorted,
                                               const int* __restrict__ btot,
                                               int* __restrict__ csr_src,
                                               int* __restrict__ rowptr,
                                               float* __restrict__ dinv,
                                               int n, int nbuck, int e) {
    __shared__ int cnt[256];
    __shared__ int s[256];
    __shared__ int fil[256];
    const int b = blockIdx.x, t = threadIdx.x;

    const int v = (t < nbuck) ? btot[t] : 0;
    s[t] = v;
    cnt[t] = 0;
    __syncthreads();
    for (int off = 1; off < 256; off <<= 1) {
        int w = (t >= off) ? s[t - off] : 0;
        __syncthreads();
        s[t] += w;
        __syncthreads();
    }
    const int hi = s[b];
    const int lo = hi - btot[b];
    __syncthreads();

    for (int p = lo + t; p < hi; p += 256) atomicAdd(&cnt[sorted[p] & 255], 1);
    __syncthreads();
    const int c = cnt[t];
    s[t] = c;
    __syncthreads();
    for (int off = 1; off < 256; off <<= 1) {
        int w = (t >= off) ? s[t - off] : 0;
        __syncthreads();
        s[t] += w;
        __syncthreads();
    }
    const int excl = s[t] - c;
    const int node = b * 256 + t;
    if (node < n) {
        rowptr[node] = lo + excl;
        dinv[node] = rsqrtf((float)(c + 1));
    }
    if (b == 0 && t == 0) rowptr[n] = e;
    fil[t] = lo + excl;
    __syncthreads();
    for (int p = lo + t; p < hi; p += 256) {
        const int pr = sorted[p];
        const int pos = atomicAdd(&fil[pr & 255], 1);
        csr_src[pos] = pr >> 8;
    }
}

// ---------------- GEMM1 (MFMA f16): g1[n,128](fp16) = dinv * (x @ W1) ----------------
__global__ __launch_bounds__(256) void k_gemm1(const float* __restrict__ x,
                                               const __half* __restrict__ wt1,
                                               const float* __restrict__ dinv,
                                               __half* __restrict__ g, int n) {
    __shared__ _Float16 Wt[128 * LDK];  // W^T [nn][kk], 34816 B
    __shared__ _Float16 xl[64 * LDK];   // x   [r][kk], 17408 B
    const int t  = threadIdx.x;
    const int wv = t >> 6;
    const int l  = t & 63;
    const int base = blockIdx.x * 64;

    {
        const uint4* Wg = (const uint4*)wt1;
#pragma unroll
        for (int i = 0; i < 8; ++i) {
            const int idx = t + 256 * i;
            const int row = idx >> 4, c8 = idx & 15;
            *(uint4*)(Wt + row * LDK + c8 * 8) = Wg[idx];
        }
    }
#pragma unroll
    for (int i = 0; i < 8; ++i) {
        const int idx = t + 256 * i;
        const int r = idx >> 5, c4 = idx & 31;
        const int row = base + r;
        float4 v = make_float4(0.f, 0.f, 0.f, 0.f);
        if (row < n) v = *(const float4*)(x + (size_t)row * 128 + c4 * 4);
        union { __half2 h2[2]; uint2 u; } pk;
        pk.h2[0] = __floats2half2_rn(v.x, v.y);
        pk.h2[1] = __floats2half2_rn(v.z, v.w);
        *(uint2*)(xl + r * LDK + c4 * 4) = pk.u;
    }
    __syncthreads();

    f32x4 acc[8];
#pragma unroll
    for (int i = 0; i < 8; ++i) acc[i] = (f32x4){0.f, 0.f, 0.f, 0.f};

    const int arow = wv * 16 + (l & 15);
    const int koff = (l >> 4) * 8;
#pragma unroll
    for (int kb = 0; kb < 4; ++kb) {
        const f16x8 a = *(const f16x8*)(xl + arow * LDK + kb * 32 + koff);
#pragma unroll
        for (int nt = 0; nt < 8; ++nt) {
            const f16x8 b = *(const f16x8*)(Wt + (nt * 16 + (l & 15)) * LDK + kb * 32 + koff);
            acc[nt] = __builtin_amdgcn_mfma_f32_16x16x32_f16(a, b, acc[nt], 0, 0, 0);
        }
    }

    // C layout: row=(l>>4)*4+i, col=nt*16+(l&15)
#pragma unroll
    for (int i = 0; i < 4; ++i) {
        const int row = base + wv * 16 + (l >> 4) * 4 + i;
        if (row < n) {
            const float dv = dinv[row];
#pragma unroll
            for (int nt = 0; nt < 8; ++nt)
                g[(size_t)row * 128 + nt * 16 + (l & 15)] = __float2half(acc[nt][i] * dv);
        }
    }
}

// ---------------- gather1: out1h[d] = fp16(relu(b1 + dd*(g1[d] + sum g1[s]))) ----------------
// wave per node; lane = (edge-slot rs=lane>>4, feat-quad fq=lane&15).
// Each 16-lane group reads one 256B source row as uint4 (16B/lane) -> 4 edges in flight,
// 1 load instr per lane per edge. shfl_xor(16,32) reduce; lanes 0..15 do self+bias+relu+store.
__global__ __launch_bounds__(256) void k_gather1(const __half* __restrict__ g,
                                                 const int* __restrict__ rowptr,
                                                 const int* __restrict__ csr_src,
                                                 const float* __restrict__ dinv,
                                                 const float* __restrict__ b1,
                                                 __half* __restrict__ out1, int n) {
    const int wave = threadIdx.x >> 6;
    const int lane = threadIdx.x & 63;
    const int d = blockIdx.x * 4 + wave;
    if (d >= n) return;
    const int rs = lane >> 4;   // 0..3
    const int fq = lane & 15;   // feats fq*8 .. fq*8+7
    const int beg = rowptr[d], end = rowptr[d + 1];
    float acc[8];
#pragma unroll
    for (int i = 0; i < 8; ++i) acc[i] = 0.f;
    for (int p = beg + rs; p < end; p += 4) {
        const int s = csr_src[p];
        const uint4 v = *(const uint4*)(g + (size_t)s * 128 + fq * 8);
        const __half2* h2 = (const __half2*)&v;
#pragma unroll
        for (int q = 0; q < 4; ++q) {
            const float2 f2 = __half22float2(h2[q]);
            acc[2 * q]     += f2.x;
            acc[2 * q + 1] += f2.y;
        }
    }
#pragma unroll
    for (int i = 0; i < 8; ++i) {
        acc[i] += __shfl_xor(acc[i], 16);
        acc[i] += __shfl_xor(acc[i], 32);
    }
    if (rs == 0) {
        const uint4 sv = *(const uint4*)(g + (size_t)d * 128 + fq * 8);
        const __half2* h2 = (const __half2*)&sv;
#pragma unroll
        for (int q = 0; q < 4; ++q) {
            const float2 f2 = __half22float2(h2[q]);
            acc[2 * q]     += f2.x;
            acc[2 * q + 1] += f2.y;
        }
        const float dd = dinv[d];
        const float4 bb0 = *(const float4*)(b1 + fq * 8);
        const float4 bb1 = *(const float4*)(b1 + fq * 8 + 4);
        const float r0 = fmaxf(fmaf(dd, acc[0], bb0.x), 0.f);
        const float r1 = fmaxf(fmaf(dd, acc[1], bb0.y), 0.f);
        const float r2 = fmaxf(fmaf(dd, acc[2], bb0.z), 0.f);
        const float r3 = fmaxf(fmaf(dd, acc[3], bb0.w), 0.f);
        const float r4 = fmaxf(fmaf(dd, acc[4], bb1.x), 0.f);
        const float r5 = fmaxf(fmaf(dd, acc[5], bb1.y), 0.f);
        const float r6 = fmaxf(fmaf(dd, acc[6], bb1.z), 0.f);
        const float r7 = fmaxf(fmaf(dd, acc[7], bb1.w), 0.f);
        union { __half2 h[4]; uint4 u; } pk;
        pk.h[0] = __floats2half2_rn(r0, r1);
        pk.h[1] = __floats2half2_rn(r2, r3);
        pk.h[2] = __floats2half2_rn(r4, r5);
        pk.h[3] = __floats2half2_rn(r6, r7);
        *(uint4*)(out1 + (size_t)d * 128 + fq * 8) = pk.u;
    }
}

// ---------------- GEMM2 (MFMA f16): g2[n,40](fp16) = dinv * (out1h @ W2), N padded to 48 ----------------
__global__ __launch_bounds__(256) void k_gemm2(const __half* __restrict__ h1,
                                               const __half* __restrict__ wt2,
                                               const float* __restrict__ dinv,
                                               __half* __restrict__ g, int n) {
    __shared__ _Float16 Wt[48 * LDK];   // 13056 B
    __shared__ _Float16 xl[64 * LDK];   // 17408 B
    const int t  = threadIdx.x;
    const int wv = t >> 6;
    const int l  = t & 63;
    const int base = blockIdx.x * 64;

    {
        const uint4* Wg = (const uint4*)wt2;   // 768 uint4
#pragma unroll
        for (int i = 0; i < 3; ++i) {
            const int idx = t + 256 * i;
            const int row = idx >> 4, c8 = idx & 15;
            *(uint4*)(Wt + row * LDK + c8 * 8) = Wg[idx];
        }
    }
#pragma unroll
    for (int i = 0; i < 4; ++i) {
        const int idx = t + 256 * i;
        const int r = idx >> 4, c8 = idx & 15;
        const int row = base + r;
        uint4 v = make_uint4(0u, 0u, 0u, 0u);
        if (row < n) v = *(const uint4*)(h1 + (size_t)row * 128 + c8 * 8);
        *(uint4*)(xl + r * LDK + c8 * 8) = v;
    }
    __syncthreads();

    f32x4 acc[3];
#pragma unroll
    for (int i = 0; i < 3; ++i) acc[i] = (f32x4){0.f, 0.f, 0.f, 0.f};

    const int arow = wv * 16 + (l & 15);
    const int koff = (l >> 4) * 8;
#pragma unroll
    for (int kb = 0; kb < 4; ++kb) {
        const f16x8 a = *(const f16x8*)(xl + arow * LDK + kb * 32 + koff);
#pragma unroll
        for (int nt = 0; nt < 3; ++nt) {
            const f16x8 b = *(const f16x8*)(Wt + (nt * 16 + (l & 15)) * LDK + kb * 32 + koff);
            acc[nt] = __builtin_amdgcn_mfma_f32_16x16x32_f16(a, b, acc[nt], 0, 0, 0);
        }
    }

#pragma unroll
    for (int i = 0; i < 4; ++i) {
        const int row = base + wv * 16 + (l >> 4) * 4 + i;
        if (row < n) {
            const float dv = dinv[row];
#pragma unroll
            for (int nt = 0; nt < 3; ++nt) {
                const int col = nt * 16 + (l & 15);
                if (col < 40)
                    g[(size_t)row * 40 + col] = __float2half(acc[nt][i] * dv);
            }
        }
    }
}

// ---------------- gather2: out[d] = b2 + dinv[d]*(g2[d] + sum g2[s]) ----------------
__global__ __launch_bounds__(256) void k_gather2(const __half2* __restrict__ g,
                                                 const int* __restrict__ rowptr,
                                                 const int* __restrict__ csr_src,
                                                 const float* __restrict__ dinv,
                                                 const float* __restrict__ b2,
                                                 float* __restrict__ out, int n) {
    const int wave = threadIdx.x >> 6;
    const int lane = threadIdx.x & 63;
    const int d = blockIdx.x * 4 + wave;
    if (d >= n) return;
    const int eg = lane / 20;          // 0..2 active, 3 idle
    const int f  = lane - eg * 20;
    const int beg = rowptr[d], end = rowptr[d + 1];
    float ax = 0.f, ay = 0.f;
    if (eg < 3) {
        for (int p = beg + eg; p < end; p += 3) {
            const int s0 = csr_src[p];
            const float2 f0 = __half22float2(g[(size_t)s0 * 20 + f]);
            ax += f0.x; ay += f0.y;
        }
    }
    ax += __shfl(ax, lane + 20) + __shfl(ax, lane + 40);
    ay += __shfl(ay, lane + 20) + __shfl(ay, lane + 40);
    if (lane < 20) {
        const float2 fs = __half22float2(g[(size_t)d * 20 + lane]);
        ax += fs.x; ay += fs.y;
        const float dd = dinv[d];
        const float2 bb = *(const float2*)(b2 + lane * 2);
        float2 r;
        r.x = fmaf(dd, ax, bb.x);
        r.y = fmaf(dd, ay, bb.y);
        *(float2*)(out + (size_t)d * 40 + lane * 2) = r;
    }
}

extern "C" void kernel_launch(void* const* d_in, const int* in_sizes, int n_in,
                              void* d_out, int out_size, void* d_ws, size_t ws_size,
                              hipStream_t stream) {
    const float* x  = (const float*)d_in[0];
    const int*   ei = (const int*)d_in[1];
    const float* W1 = (const float*)d_in[2];
    const float* b1 = (const float*)d_in[3];
    const float* W2 = (const float*)d_in[4];
    const float* b2 = (const float*)d_in[5];
    float* out = (float*)d_out;

    const int n = in_sizes[0] / 128;   // 50000
    const int e = in_sizes[1] / 2;     // 800000
    const int* src = ei;
    const int* dst = ei + e;

    const int n_pad = ((n + 63) / 64) * 64;
    const int e_pad = ((e + 63) / 64) * 64;
    const int NB    = (e + EPB - 1) / EPB;        // 391
    const int nbuck = (n + 255) >> 8;             // 196
    const int nbpad = ((NB + 63) / 64) * 64;      // 448

    // ws layout (4B units):
    //   dinv[n_pad] | rowptr[n_pad+64] | csr_src[e_pad] | g1[n_pad*128 fp16]
    //   | out1h[n_pad*128 fp16] | wt1h[128*128 fp16] | wt2h[48*128 fp16]
    // sorted/Hmat/Off/btot overlay g1 (dead before k_gemm1); g2 overlays g1 (dead after gather1).
    float*   ws      = (float*)d_ws;
    float*   dinv    = ws;
    int*     rowptr  = (int*)(ws + n_pad);
    int*     csr_src = rowptr + n_pad + 64;
    __half*  g1      = (__half*)(csr_src + e_pad);       // n_pad*128 fp16
    __half*  out1h   = g1 + (size_t)n_pad * 128;
    __half*  wt1h    = out1h + (size_t)n_pad * 128;
    __half*  wt2h    = wt1h + 128 * 128;
    int*     sorted  = (int*)g1;                         // overlay: e_pad ints (packed)
    int*     Hmat    = (int*)g1 + e_pad;                 // overlay
    int*     Off     = Hmat + nbuck * nbpad;             // overlay
    int*     btot    = Off + nbuck * nbpad;              // overlay
    __half2* g2      = (__half2*)g1;                     // overlay

    const int nb_rows = (n + 63) / 64;
    const int nb_g    = (n + 3) / 4;

    // weight pre-convert (independent of everything else)
    k_wcvt<<<(128 * 128 + 48 * 128 + 255) / 256, 256, 0, stream>>>(W1, W2, wt1h, wt2h);

    // CSR build: 2-level bucket sort, packed payload, zero global atomics
    k_hist <<<NB,    256, 0, stream>>>(dst, Hmat, e, nbuck, nbpad);
    k_bscan<<<nbuck, 256, 0, stream>>>(Hmat, Off, btot, NB, nbpad);
    k_scat <<<NB,    256, 0, stream>>>(src, dst, Off, btot, sorted, e, nbuck, nbpad);
    k_bsort<<<nbuck, 256, 0, stream>>>(sorted, btot, csr_src, rowptr, dinv, n, nbuck, e);

    // layer 1
    k_gemm1  <<<nb_rows, 256, 0, stream>>>(x, wt1h, dinv, g1, n);
    k_gather1<<<nb_g, 256, 0, stream>>>(g1, rowptr, csr_src, dinv, b1, out1h, n);

    // layer 2
    k_gemm2  <<<nb_rows, 256, 0, stream>>>(out1h, wt2h, dinv, (__half*)g2, n);
    k_gather2<<<nb_g, 256, 0, stream>>>(g2, rowptr, csr_src, dinv, b2, out, n);
}